// Round 11
// baseline (174.230 us; speedup 1.0000x reference)
//
#include <hip/hip_runtime.h>

typedef _Float16 f16;
typedef _Float16 f16x8 __attribute__((ext_vector_type(8)));
typedef _Float16 f16x4 __attribute__((ext_vector_type(4)));
typedef float f32x4 __attribute__((ext_vector_type(4)));
typedef float f32x16 __attribute__((ext_vector_type(16)));

#define GDIM 52
#define GG 2704          // 52*52
#define CIN 256
#define CMID 512
#define COUT 75
#define NIMG 16
#define SPT 192          // conv1 spatial tile
#define NSPB 15          // ceil(2704/192)
#define PH 60            // padded rows in x16p
#define PW 54            // padded cols

#define SLAB_SZ 24576    // one slab buffer: 4 ci-slots x 384 pix x 16 B

#define VMCNT0 asm volatile("s_waitcnt vmcnt(0)" ::: "memory")
#define SB0 __builtin_amdgcn_sched_barrier(0)

__device__ __forceinline__ float sigmoidf_(float x) {
    return 1.0f / (1.0f + __expf(-x));
}

__device__ __forceinline__ void gload16(const void* g, void* l) {
    __builtin_amdgcn_global_load_lds(
        (const __attribute__((address_space(1))) unsigned int*)g,
        (__attribute__((address_space(3))) unsigned int*)l, 16, 0, 0);
}

// ---- zero the pad borders of x16p (rows 0,53..59 fully; cols 0,53 rows 1..52) ----
__global__ __launch_bounds__(256) void k_zero_border(f16* __restrict__ x16p) {
    int ic = blockIdx.x;             // img*8 + ck
    int tid = threadIdx.x;
    f16x8 z;
#pragma unroll
    for (int k = 0; k < 8; ++k) z[k] = (f16)0;
    for (int j = tid; j < 536; j += 256) {
        int row, col;
        if (j < 432) { int r = j / 54; row = (r == 0) ? 0 : 52 + r; col = j % 54; }
        else { int k = j - 432; row = 1 + (k >> 1); col = (k & 1) * 53; }
        f16* p = x16p + (((size_t)ic * PH + row) * PW + col) * 32;
#pragma unroll
        for (int q = 0; q < 4; ++q) *(f16x8*)(p + q * 8) = z;
    }
}

// ---- prep: x [img][ci][hw] f32 -> x16p [img][ck][h+1][w+1][32ci] f16 (padded) ----
__global__ __launch_bounds__(256) void k_prep_x(const float* __restrict__ x,
                                                f16* __restrict__ x16p) {
    __shared__ float ls[32][133];
    int hw0 = blockIdx.x * 128, ck = blockIdx.y, img = blockIdx.z;
    int tid = threadIdx.x;
    const float* xb = x + ((size_t)img * CIN + ck * 32) * GG;
#pragma unroll
    for (int i = 0; i < 16; ++i) {
        int idx = tid + i * 256;
        int r = idx >> 7, c = idx & 127;
        int hw = hw0 + c;
        ls[r][c] = (hw < GG) ? xb[(size_t)r * GG + hw] : 0.0f;
    }
    __syncthreads();
    int col = tid >> 1, half = tid & 1;
    int hw = hw0 + col;
    if (hw < GG) {
        int h = hw / GDIM, w = hw % GDIM;
        f16* dst = x16p + ((((size_t)img * 8 + ck) * PH + h + 1) * PW + (w + 1)) * 32 + half * 16;
        f16x8 o0, o1;
#pragma unroll
        for (int j = 0; j < 8; ++j) o0[j] = (f16)ls[half * 16 + j][col];
#pragma unroll
        for (int j = 0; j < 8; ++j) o1[j] = (f16)ls[half * 16 + 8 + j][col];
        *(f16x8*)dst = o0;
        *(f16x8*)(dst + 8) = o1;
    }
}

// ---- prep: weights + BN fold.  w16 layout [tap][ck][co][32ci] ----
__global__ __launch_bounds__(256) void k_prep_w(
    const float* __restrict__ w1, const float* __restrict__ w2,
    const float* __restrict__ gamma, const float* __restrict__ beta,
    const float* __restrict__ mean, const float* __restrict__ var,
    f16* __restrict__ w16, f16* __restrict__ w2_16,
    float* __restrict__ bnscale, float* __restrict__ bnshift) {
    int i = blockIdx.x * 256 + threadIdx.x;   // exactly 9*8*512*32 = 1,179,648 threads
    int cl = i & 31;
    int co = (i >> 5) & 511;
    int ckt = i >> 14;          // tap*8 + ck
    int ck = ckt & 7, tap = ckt >> 3;
    int ci = ck * 32 + cl;
    w16[i] = (f16)w1[(size_t)co * 2304 + ci * 9 + tap];
    if (i < COUT * CMID) w2_16[i] = (f16)w2[i];
    if (i < CMID) {
        float s = gamma[i] * rsqrtf(var[i] + 1e-5f);
        bnscale[i] = s;
        bnshift[i] = beta[i] - mean[i] * s;
    }
}

// tap pixel delta (f16 units) for tap literal T
#define TPX(T) ((((T) / 3 - 1) * PW + ((T) % 3) - 1) * 8)

// ---- conv1: 3x3 + BN + LeakyReLU -> y16 [quarter][img][n][128co] ----
// 256 thr / 4 waves (2 wm x 2 wn); block 128co x 192sp; wave 64co x 96sp.
// 32x32x16 MFMA (layouts verified in R5). A: global->reg at use (L1/L2-hot).
// B: DMA slab, dbuf per ck. 3 independent blocks/CU (private barriers) ->
// decorrelated stalls; one vmcnt(0)+barrier per ck; SB0 per tap (anti-hoist).
__global__ __launch_bounds__(256, 3) void k_conv1(
    const f16* __restrict__ x16p, const f16* __restrict__ w16,
    const float* __restrict__ bnscale, const float* __restrict__ bnshift,
    f16* __restrict__ y16) {
    __shared__ __align__(16) char smem[50688];   // slab dbuf 49152 / epilogue tb
    int img = blockIdx.x / NSPB, sb = blockIdx.x % NSPB;
    int n0 = sb * SPT;
    int h_lo = n0 / GDIM;
    int quarter = blockIdx.y;
    int co0 = quarter * 128;
    int tid = threadIdx.x;
    int lane = tid & 63, wave = tid >> 6;
    int wm = wave >> 1, wn = wave & 1;
    int l31 = lane & 31, hi = lane >> 5;

    int roff[3];   // pixel*8 (f16 units within one ci-slot row)
#pragma unroll
    for (int nt = 0; nt < 3; ++nt) {
        int n = n0 + wn * 96 + nt * 32 + l31;
        int nc = n < GG ? n : GG - 1;
        int hh = nc / GDIM, ww = nc % GDIM;
        roff[nt] = ((hh - h_lo + 1) * PW + (ww + 1)) * 8;
    }

    f32x16 acc[2][3];
#pragma unroll
    for (int a = 0; a < 2; ++a)
#pragma unroll
        for (int b = 0; b < 3; ++b)
#pragma unroll
            for (int i = 0; i < 16; ++i) acc[a][b][i] = 0.f;

    const f16* xbase = x16p + ((size_t)img * 8 * PH + h_lo) * (PW * 32);
    // lane base into one (tap,ck) A-tile (512co x 32ci): co row + hi half
    const f16* wAfrag = w16 + ((size_t)co0 + wm * 64 + l31) * 32 + hi * 8;

    // ---- prologue: issue slab(0) DMA ----
    {
        f16* sd = (f16*)smem;
#pragma unroll
        for (int p = 0; p < 6; ++p) {
            int c = p * 256 + tid;
            int s = c / 384, pix = c % 384;
            gload16(xbase + (size_t)pix * 32 + s * 8, sd + (size_t)c * 8);
        }
    }

    for (int ck = 0; ck < 8; ++ck) {
        VMCNT0;                       // slab(ck) done (issued a full ck ago)
        __builtin_amdgcn_s_barrier();
        SB0;
        if (ck < 7) {                 // issue slab(ck+1) into the other buffer
            const f16* sg = xbase + (size_t)(ck + 1) * (PH * PW * 32);
            f16* sd = (f16*)(smem + ((ck + 1) & 1) * SLAB_SZ);
#pragma unroll
            for (int p = 0; p < 6; ++p) {
                int c = p * 256 + tid;
                int s = c / 384, pix = c % 384;
                gload16(sg + (size_t)pix * 32 + s * 8, sd + (size_t)c * 8);
            }
        }
        SB0;
        const f16* Sb = (const f16*)(smem + (ck & 1) * SLAB_SZ);
#pragma unroll
        for (int tap = 0; tap < 9; ++tap) {
            const f16* ap = wAfrag + (size_t)(tap * 8 + ck) * 16384;
            const f16* bp0 = Sb + hi * 3072 + TPX(tap);         // kk=0 slots
            const f16* bp1 = Sb + (2 + hi) * 3072 + TPX(tap);   // kk=1 slots
            // ---- kk = 0 (ci 0..15) ----
            {
                f16x8 b0 = *(const f16x8*)(bp0 + roff[0]);
                f16x8 b1 = *(const f16x8*)(bp0 + roff[1]);
                f16x8 b2 = *(const f16x8*)(bp0 + roff[2]);
                f16x8 a0 = *(const f16x8*)(ap);
                f16x8 a1 = *(const f16x8*)(ap + 1024);
                __builtin_amdgcn_s_setprio(1);
                acc[0][0] = __builtin_amdgcn_mfma_f32_32x32x16_f16(a0, b0, acc[0][0], 0, 0, 0);
                acc[1][0] = __builtin_amdgcn_mfma_f32_32x32x16_f16(a1, b0, acc[1][0], 0, 0, 0);
                acc[0][1] = __builtin_amdgcn_mfma_f32_32x32x16_f16(a0, b1, acc[0][1], 0, 0, 0);
                acc[1][1] = __builtin_amdgcn_mfma_f32_32x32x16_f16(a1, b1, acc[1][1], 0, 0, 0);
                acc[0][2] = __builtin_amdgcn_mfma_f32_32x32x16_f16(a0, b2, acc[0][2], 0, 0, 0);
                acc[1][2] = __builtin_amdgcn_mfma_f32_32x32x16_f16(a1, b2, acc[1][2], 0, 0, 0);
                __builtin_amdgcn_s_setprio(0);
            }
            // ---- kk = 1 (ci 16..31) ----
            {
                f16x8 b0 = *(const f16x8*)(bp1 + roff[0]);
                f16x8 b1 = *(const f16x8*)(bp1 + roff[1]);
                f16x8 b2 = *(const f16x8*)(bp1 + roff[2]);
                f16x8 a0 = *(const f16x8*)(ap + 16);
                f16x8 a1 = *(const f16x8*)(ap + 1040);
                __builtin_amdgcn_s_setprio(1);
                acc[0][0] = __builtin_amdgcn_mfma_f32_32x32x16_f16(a0, b0, acc[0][0], 0, 0, 0);
                acc[1][0] = __builtin_amdgcn_mfma_f32_32x32x16_f16(a1, b0, acc[1][0], 0, 0, 0);
                acc[0][1] = __builtin_amdgcn_mfma_f32_32x32x16_f16(a0, b1, acc[0][1], 0, 0, 0);
                acc[1][1] = __builtin_amdgcn_mfma_f32_32x32x16_f16(a1, b1, acc[1][1], 0, 0, 0);
                acc[0][2] = __builtin_amdgcn_mfma_f32_32x32x16_f16(a0, b2, acc[0][2], 0, 0, 0);
                acc[1][2] = __builtin_amdgcn_mfma_f32_32x32x16_f16(a1, b2, acc[1][2], 0, 0, 0);
                __builtin_amdgcn_s_setprio(0);
            }
            SB0;
        }
    }
    // ---- epilogue: BN + leaky -> LDS transpose (stride 132 f16) -> linear y16 ----
    VMCNT0;
    __syncthreads();
    f16* tb = (f16*)smem;
#pragma unroll
    for (int mt = 0; mt < 2; ++mt)
#pragma unroll
        for (int q = 0; q < 4; ++q) {
            int co_l = wm * 64 + mt * 32 + q * 8 + hi * 4;
            f32x4 sc = *(const f32x4*)(bnscale + co0 + co_l);
            f32x4 sh = *(const f32x4*)(bnshift + co0 + co_l);
#pragma unroll
            for (int nt = 0; nt < 3; ++nt) {
                int pix_l = wn * 96 + nt * 32 + l31;
                f16x4 o;
#pragma unroll
                for (int i = 0; i < 4; ++i) {
                    float v = acc[mt][nt][q * 4 + i] * sc[i] + sh[i];
                    o[i] = (f16)(v > 0.f ? v : 0.1f * v);
                }
                *(f16x4*)(tb + pix_l * 132 + co_l) = o;
            }
        }
    __syncthreads();
    int valid = GG - n0; if (valid > SPT) valid = SPT;
    f16* yb = y16 + (size_t)quarter * (NIMG * (size_t)GG * 128) +
              ((size_t)img * GG + n0) * 128;
#pragma unroll
    for (int p = 0; p < 12; ++p) {
        int u = p * 256 + tid, pl = u >> 4, slot = u & 15;
        if (pl < valid)
            *(f16x8*)(yb + (size_t)pl * 128 + slot * 8) =
                *(const f16x8*)(tb + pl * 132 + slot * 8);
    }
}

// ---- conv2 (1x1, K=512) + bias + YOLO decode. 256 thr / 4 waves, 128 n per block ----
__global__ __launch_bounds__(256) void k_conv2(
    const f16* __restrict__ y16, const f16* __restrict__ w2_16,
    const float* __restrict__ b2, float* __restrict__ out) {
    __shared__ float ct[128][81];   // 41472 B
    int img = blockIdx.x / 22, nb = blockIdx.x % 22;
    int n0 = nb * 128;
    int tid = threadIdx.x;
    int lane = tid & 63, wave = tid >> 6;
    int l15 = lane & 15, kg = lane >> 4;

    f32x4 acc[5][2];
#pragma unroll
    for (int a = 0; a < 5; ++a)
#pragma unroll
        for (int b = 0; b < 2; ++b) {
            acc[a][b][0] = 0.f; acc[a][b][1] = 0.f;
            acc[a][b][2] = 0.f; acc[a][b][3] = 0.f;
        }

    int nn[2];
#pragma unroll
    for (int nf = 0; nf < 2; ++nf) {
        int n = n0 + wave * 32 + nf * 16 + l15;
        nn[nf] = n < GG ? n : GG - 1;
    }
    for (int c0 = 0; c0 < CMID; c0 += 32) {
        const f16* yb = y16 + (size_t)(c0 >> 7) * (NIMG * (size_t)GG * 128) +
                        (size_t)img * GG * 128;
        int c = c0 & 127;
        f16x8 af[5];
#pragma unroll
        for (int mf = 0; mf < 5; ++mf) {
            int co = mf * 16 + l15;
            if (co < COUT)
                af[mf] = *(const f16x8*)(w2_16 + (size_t)co * CMID + c0 + kg * 8);
            else {
#pragma unroll
                for (int k = 0; k < 8; ++k) af[mf][k] = (f16)0;
            }
        }
#pragma unroll
        for (int nf = 0; nf < 2; ++nf) {
            f16x8 bf = *(const f16x8*)(yb + (size_t)nn[nf] * 128 + c + kg * 8);
#pragma unroll
            for (int mf = 0; mf < 5; ++mf)
                acc[mf][nf] = __builtin_amdgcn_mfma_f32_16x16x32_f16(
                    af[mf], bf, acc[mf][nf], 0, 0, 0);
        }
    }
#pragma unroll
    for (int mf = 0; mf < 5; ++mf)
#pragma unroll
        for (int nf = 0; nf < 2; ++nf)
            *(f32x4*)(&ct[wave * 32 + nf * 16 + l15][mf * 16 + kg * 4]) = acc[mf][nf];
    __syncthreads();
    // decode: 384 (anchor, n) items over 256 threads
    for (int j = tid; j < 384; j += 256) {
        int a = j >> 7, nl = j & 127;
        int n = n0 + nl;
        if (n >= GG) continue;
        const float* t = &ct[nl][a * 25];
        float tv[25];
#pragma unroll
        for (int q = 0; q < 25; ++q) tv[q] = t[q] + b2[a * 25 + q];
        int h = n / GDIM, w = n % GDIM;
        const float AW[3] = {10.f, 16.f, 33.f};
        const float AH[3] = {13.f, 30.f, 23.f};
        float bx = (sigmoidf_(tv[0]) + (float)w) * 8.0f;
        float by = (sigmoidf_(tv[1]) + (float)h) * 8.0f;
        float bw_ = __expf(tv[2]) * AW[a];
        float bh_ = __expf(tv[3]) * AH[a];
        float* o = out + ((size_t)img * 8112 + (size_t)a * GG + n) * 25;
        o[0] = bx; o[1] = by; o[2] = bw_; o[3] = bh_;
        o[4] = sigmoidf_(tv[4]);
#pragma unroll
        for (int q = 0; q < 20; ++q) o[5 + q] = sigmoidf_(tv[5 + q]);
    }
}

extern "C" void kernel_launch(void* const* d_in, const int* in_sizes, int n_in,
                              void* d_out, int out_size, void* d_ws, size_t ws_size,
                              hipStream_t stream) {
    (void)in_sizes; (void)n_in; (void)out_size; (void)ws_size;
    const float* x     = (const float*)d_in[0];
    const float* w1    = (const float*)d_in[1];
    const float* gamma = (const float*)d_in[2];
    const float* beta  = (const float*)d_in[3];
    const float* mean  = (const float*)d_in[4];
    const float* var   = (const float*)d_in[5];
    const float* w2    = (const float*)d_in[6];
    const float* b2    = (const float*)d_in[7];
    float* out = (float*)d_out;

    char* ws = (char*)d_ws;
    // x16p: 16*8*60*54*32*2 = 26,542,080 B
    f16* x16p     = (f16*)(ws);
    f16* w16      = (f16*)(ws + 26542080);     // 2,359,296 B
    f16* w2_16    = (f16*)(ws + 28901376);     //    76,800 B
    float* bnscale = (float*)(ws + 28978176);  //     2,048 B
    float* bnshift = (float*)(ws + 28980224);  //     2,048 B
    f16* y16      = (f16*)(ws + 28982272);     // 44,302,336 B (total ~73.3 MB)

    k_zero_border<<<NIMG * 8, 256, 0, stream>>>(x16p);
    k_prep_x<<<dim3(22, 8, NIMG), 256, 0, stream>>>(x, x16p);
    k_prep_w<<<4608, 256, 0, stream>>>(w1, w2, gamma, beta, mean, var,
                                       w16, w2_16, bnscale, bnshift);
    k_conv1<<<dim3(NIMG * NSPB, 4), 256, 0, stream>>>(x16p, w16, bnscale,
                                                      bnshift, y16);
    k_conv2<<<NIMG * 22, 256, 0, stream>>>(y16, w2_16, b2, out);
}